// Round 3
// baseline (308.932 us; speedup 1.0000x reference)
//
#include <hip/hip_runtime.h>
#include <hip/hip_bf16.h>
#include <cstddef>

// MHAttention forward, MI355X/gfx950.
// Dtype contract (R0-R3): inputs fp32 (toks, W*, b*; masks int32), OUTPUT fp32.
// Internals: bf16 MFMA fragments, fp32 accumulation.
// R14 -> R15 post-mortem: XCD remap cut FETCH 132->118MB but dur unchanged --
// kernel is NOT BW-bound (10% HBM). 60% of cycles are pure stall: 2 full-block
// barriers per K-tile + a 1-body-slack vmcnt wait on staging loads that miss
// L2 (~900cy). R15 restructure: each wave owns its 16 q-rows END-TO-END.
// QK^T per wave = its q-block vs ALL 64 keys (same 8 MFMA); softmax lsum is a
// per-lane scalar; P round-trips a WAVE-PRIVATE LDS slab (same-wave DS order +
// lgkmcnt, NO barrier); PV = wave's P vs all of V. Cross-wave sync in the loop
// is ONLY the K/V staging flip -> ONE lgkm barrier/iter (was 2), and the final
// cross-wave lsum exchange disappears. Staging prefetch deepened to distance-2
// (two NAMED reg sets, loop unrolled x2 -> no scratch, R11 lesson): vmcnt wait
// now has ~2 bodies of slack. LDS layout/patterns unchanged (measured 0 confl).

typedef __bf16 bf16_8 __attribute__((ext_vector_type(8)));
typedef float f32x4 __attribute__((ext_vector_type(4)));
typedef short s16x4 __attribute__((ext_vector_type(4)));
typedef short s16x8 __attribute__((ext_vector_type(8)));

#define HID 768
#define NHEADS 12
#define HD 64
#define BATCH 4
#define SEQ 2048
#define NEGBIG2 (-1.44269504e31f)  // -1e31 * log2e, exp2 -> 0
#define SCALE2 0.18033688f         // 0.125 * log2e

#define KT 64            // keys per LDS tile (attn)
#define NKT (SEQ / KT)
#define STR 68           // attn LDS row stride (elems): 136B rows -> 0 conflicts (R10)
#define ASTR 40          // proj LDS row stride (elems): 80B rows, 16B-aligned frags

static __device__ __forceinline__ f32x4 mfma16x16x32(bf16_8 a, bf16_8 b, f32x4 c) {
  return __builtin_amdgcn_mfma_f32_16x16x32_bf16(a, b, c, 0, 0, 0);
}

// Workgroup barrier waiting LDS ops only — does NOT drain outstanding global
// loads (vmcnt). "memory" clobber pins compiler-level ordering of LDS ops.
static __device__ __forceinline__ void lds_barrier() {
  __asm__ volatile("s_waitcnt lgkmcnt(0)\n\ts_barrier" ::: "memory");
}

// Per-wave LDS flush: own ds_writes complete (cross-lane-within-wave visibility
// for the private P slab). No s_barrier.
static __device__ __forceinline__ void lds_flush() {
  __asm__ volatile("s_waitcnt lgkmcnt(0)" ::: "memory");
}

static __device__ __forceinline__ float fast_exp2(float x) {
#if __has_builtin(__builtin_amdgcn_exp2f)
  return __builtin_amdgcn_exp2f(x);
#else
  return __expf(x * 0.69314718f);
#endif
}

static __device__ __forceinline__ s16x4 pack_bf16x4(f32x4 p) {
  s16x4 o;
#pragma unroll
  for (int i = 0; i < 4; ++i) {
    __bf16 b = (__bf16)p[i];
    o[i] = __builtin_bit_cast(short, b);
  }
  return o;
}

// two b64 LDS reads -> one bf16_8 fragment (rows are 8B-aligned at STR=68)
static __device__ __forceinline__ bf16_8 cat2(const __bf16* p) {
  s16x4 lo = *(const s16x4*)p;
  s16x4 hi = *(const s16x4*)(p + 4);
  s16x8 v = __builtin_shufflevector(lo, hi, 0, 1, 2, 3, 4, 5, 6, 7);
  return __builtin_bit_cast(bf16_8, v);
}

// one 16B register chunk -> two b64 LDS writes
static __device__ __forceinline__ void write2(__bf16* p, s16x8 v) {
  *(s16x4*)p = __builtin_shufflevector(v, v, 0, 1, 2, 3);
  *(s16x4*)(p + 4) = __builtin_shufflevector(v, v, 4, 5, 6, 7);
}

static __device__ __forceinline__ bf16_8 cvt_a_frag(const float* p) {
  f32x4 af0 = *(const f32x4*)p;
  f32x4 af1 = *(const f32x4*)(p + 4);
  bf16_8 a;
  a[0] = (__bf16)af0[0]; a[1] = (__bf16)af0[1];
  a[2] = (__bf16)af0[2]; a[3] = (__bf16)af0[3];
  a[4] = (__bf16)af1[0]; a[5] = (__bf16)af1[1];
  a[6] = (__bf16)af1[2]; a[7] = (__bf16)af1[3];
  return a;
}

// ---------- mask -> additive kadd2 (0 or -1e31*log2e), fp32, global ----------
__global__ __launch_bounds__(256) void mask_kadd(const int* __restrict__ masks,
                                                 float* __restrict__ kaddG) {
  int i = blockIdx.x * 256 + threadIdx.x;
  kaddG[i] = masks[i] ? 0.0f : NEGBIG2;
}

// ---------- 3x 768x768 transpose + fp32->bf16, one launch (z picks matrix) ----------
__global__ __launch_bounds__(256) void transpose768x3(const float* __restrict__ Wq,
                                                      const float* __restrict__ Wk,
                                                      const float* __restrict__ Wv,
                                                      __bf16* __restrict__ WtBase) {
  const float* in = blockIdx.z == 0 ? Wq : (blockIdx.z == 1 ? Wk : Wv);
  __bf16* out = WtBase + (size_t)blockIdx.z * HID * HID;
  __shared__ __bf16 tile[32][33];
  int bx = blockIdx.x * 32, by = blockIdx.y * 32;
  int tx = threadIdx.x, ty = threadIdx.y;  // block (32,8)
#pragma unroll
  for (int r = 0; r < 32; r += 8)
    tile[ty + r][tx] = (__bf16)in[(size_t)(by + ty + r) * HID + bx + tx];
  __syncthreads();
#pragma unroll
  for (int r = 0; r < 32; r += 8)
    out[(size_t)(bx + ty + r) * HID + by + tx] = tile[tx][ty + r];
}

// ---------- K+V projection, m97-style: 256 threads, 64 rows x 64 cols (1 head) ----------
__global__ __launch_bounds__(256, 4) void proj_kv(const float* __restrict__ toks,
                                                  const __bf16* __restrict__ WtK,
                                                  const float* __restrict__ bk,
                                                  const __bf16* __restrict__ WtV,
                                                  const float* __restrict__ bv,
                                                  __bf16* __restrict__ Kout,
                                                  __bf16* __restrict__ Vtout,
                                                  int head0, int hm) {
  __shared__ __align__(16) __bf16 ldsA[2][64 * ASTR];  // 2 x 5120 B
  int tid = threadIdx.x;
  int w = tid >> 6, lane = tid & 63, l16 = lane & 15, quad = lane >> 4;
  int m0 = blockIdx.x * 64;
  int hl = blockIdx.y, h = head0 + hl;
  int srow = tid >> 2, scg = tid & 3;  // staging: row 0..63, 8-elem group 0..3
  const float* asrc = toks + (size_t)(m0 + srow) * HID + scg * 8;
  const __bf16* bKrow = WtK + (size_t)(h * 64 + w * 16 + l16) * HID + quad * 8;
  const __bf16* bVrow = WtV + (size_t)(h * 64 + w * 16 + l16) * HID + quad * 8;
  f32x4 zero = {0.f, 0.f, 0.f, 0.f};
  f32x4 aK[4], aV[4];
#pragma unroll
  for (int mt = 0; mt < 4; ++mt) { aK[mt] = zero; aV[mt] = zero; }

  // stage chunk 0
  *(bf16_8*)(&ldsA[0][srow * ASTR + scg * 8]) = cvt_a_frag(asrc);
  __syncthreads();

  const int NCH = HID / 32;  // 24
  for (int t = 0; t < NCH; ++t) {
    int b = t & 1;
    int kk = t * 32;
    // prefetch chunk t+1 (named register, consumed by ds_write at bottom)
    bf16_8 areg;
    if (t + 1 < NCH) areg = cvt_a_frag(asrc + kk + 32);
    // B frags for this wave's 16 cols (L2-hot weights)
    bf16_8 bkf = *(const bf16_8*)(bKrow + kk);
    bf16_8 bvf = *(const bf16_8*)(bVrow + kk);
#pragma unroll
    for (int mt = 0; mt < 4; ++mt) {
      // A frag: lane holds toks[m = mt*16+l16][k = quad*8+j]
      bf16_8 af = *(const bf16_8*)(&ldsA[b][(mt * 16 + l16) * ASTR + quad * 8]);
      aK[mt] = mfma16x16x32(af, bkf, aK[mt]);
      aV[mt] = mfma16x16x32(af, bvf, aV[mt]);
    }
    if (t + 1 < NCH) {
      *(bf16_8*)(&ldsA[b ^ 1][srow * ASTR + scg * 8]) = areg;
      lds_barrier();
    }
  }

  int d = w * 16 + l16;
  float bnK = bk[h * 64 + d];
  float bnV = bv[h * 64 + d];
#pragma unroll
  for (int mt = 0; mt < 4; ++mt) {
#pragma unroll
    for (int r = 0; r < 4; ++r) {
      int m = m0 + mt * 16 + quad * 4 + r;
      int b = m >> 11;            // batch (64-row tiles never cross batch)
      int s = m & (SEQ - 1);
      Kout[(((size_t)b * hm + hl) * SEQ + s) * HD + d] = (__bf16)(aK[mt][r] + bnK);
      Vtout[(((size_t)b * hm + hl) * HD + d) * SEQ + s] = (__bf16)(aV[mt][r] + bnV);
    }
  }
}

// ---------- fused Q-proj + flash attention: per-wave-q, 1 barrier/iter ----------
// Block 256 threads (4 waves) per (bh, 64-query tile). Wave w owns q-rows
// w*16..+16 end-to-end: Q-proj -> private-slab transpose -> QK^T vs ALL 64 keys
// -> per-lane softmax -> P in private slab (lgkm only, no barrier) -> PV vs all
// of V -> normalized output. Only cross-wave state: K/V staging double-buffer,
// refreshed with distance-2 prefetch in two NAMED reg sets (loop unrolled x2).
__global__ __launch_bounds__(256, 3) void attn_fused(const float* __restrict__ toks,
                                                     const __bf16* __restrict__ WtQ,
                                                     const float* __restrict__ bq,
                                                     const __bf16* __restrict__ Kbuf,
                                                     const __bf16* __restrict__ Vtbuf,
                                                     const float* __restrict__ kaddG,
                                                     float* __restrict__ out,
                                                     int head0, int hm) {
  __shared__ __align__(16) __bf16 ldsK[2][64 * STR];  // 2 x 8704 B
  __shared__ __align__(16) __bf16 ldsV[2][64 * STR];  // 2 x 8704 B
  __shared__ __align__(16) __bf16 ldsQP[64 * STR];    // 4 wave-private 16-row slabs
  int tid = threadIdx.x;
  int w = tid >> 6, lane = tid & 63, l16 = lane & 15, quad = lane >> 4;

  // XCD-locality remap (kept from R14; FETCH 132->118MB, no harm)
  int nwg = gridDim.x * gridDim.y * gridDim.z;           // 1536 (A) / 128 (B)
  int hwf = blockIdx.x + gridDim.x * (blockIdx.y + gridDim.y * blockIdx.z);
  int lg = (hwf & 7) * (nwg >> 3) + (hwf >> 3);          // nwg % 8 == 0 both tiers
  int q0 = (lg & (gridDim.x - 1)) * 64;                  // gridDim.x = 32 (pow2)
  int grp = lg / gridDim.x;                              // b*hm + hl
  int hl = grp % hm, bz = grp / hm;
  int h = head0 + hl;

  const float* kb = kaddG + (size_t)bz * SEQ;
  f32x4 zero = {0.f, 0.f, 0.f, 0.f};

  const __bf16* Kb = Kbuf + ((size_t)bz * hm + hl) * SEQ * HD;
  const __bf16* Vb = Vtbuf + ((size_t)bz * hm + hl) * HD * SEQ;
  __bf16* Pw = &ldsQP[(w * 16) * STR];  // this wave's private 16 x STR slab

  // --- Q projection: wave w -> rows q0 + w*16 .. +16, all 64 d.
  // Output D-layout -> private slab (row = q-local) -> re-read as B-frags.
  {
    const float* arow = toks + ((size_t)bz * SEQ + q0 + w * 16 + l16) * HID + quad * 8;
    const __bf16* brow = WtQ + (size_t)(h * 64 + l16) * HID + quad * 8;
    f32x4 qa[4] = {zero, zero, zero, zero};
    for (int kk = 0; kk < HID; kk += 32) {
      bf16_8 a = cvt_a_frag(arow + kk);
#pragma unroll
      for (int t = 0; t < 4; ++t)
        qa[t] = mfma16x16x32(a, *(const bf16_8*)(brow + (size_t)t * 16 * HID + kk), qa[t]);
    }
#pragma unroll
    for (int t = 0; t < 4; ++t) {
      float bn = bq[h * 64 + t * 16 + l16];
#pragma unroll
      for (int r = 0; r < 4; ++r)
        Pw[(quad * 4 + r) * STR + t * 16 + l16] = (__bf16)(qa[t][r] + bn);
    }
  }
  lds_flush();  // private slab: own wave's writes visible to own lanes

  // Q B-frags: lane holds Q[q = w*16+l16][d = half*32+quad*8+j]
  bf16_8 qf[2];
#pragma unroll
  for (int half = 0; half < 2; ++half)
    qf[half] = cat2(&Pw[l16 * STR + half * 32 + quad * 8]);
  float actq = (kb[q0 + w * 16 + l16] == 0.0f) ? 1.0f : 0.0f;

  // --- stage tile 0 direct (K rows = keys, V rows = d) + prefetch tile 1 ---
  int srow = tid >> 3, sc = tid & 7;  // srow 0..31 (+32), 8-elem chunk 0..7
  {
    s16x8 k0 = *(const s16x8*)(Kb + (size_t)srow * HD + sc * 8);
    s16x8 k1 = *(const s16x8*)(Kb + (size_t)(srow + 32) * HD + sc * 8);
    s16x8 v0 = *(const s16x8*)(Vb + (size_t)srow * SEQ + sc * 8);
    s16x8 v1 = *(const s16x8*)(Vb + (size_t)(srow + 32) * SEQ + sc * 8);
    write2(&ldsK[0][srow * STR + sc * 8], k0);
    write2(&ldsK[0][(srow + 32) * STR + sc * 8], k1);
    write2(&ldsV[0][srow * STR + sc * 8], v0);
    write2(&ldsV[0][(srow + 32) * STR + sc * 8], v1);
  }
  // set A <- tile 1 (named regs; consumed at bottom of iter 0)
  s16x8 kA0 = *(const s16x8*)(Kb + (size_t)(KT + srow) * HD + sc * 8);
  s16x8 kA1 = *(const s16x8*)(Kb + (size_t)(KT + srow + 32) * HD + sc * 8);
  s16x8 vA0 = *(const s16x8*)(Vb + (size_t)srow * SEQ + KT + sc * 8);
  s16x8 vA1 = *(const s16x8*)(Vb + (size_t)(srow + 32) * SEQ + KT + sc * 8);
  s16x8 kB0, kB1, vB0, vB1;
  lds_barrier();  // tile 0 visible (does not drain set-A vmcnt)

  float lsum = 0.f;
  f32x4 acc[4];
#pragma unroll
  for (int dt = 0; dt < 4; ++dt) acc[dt] = zero;

  // per-iter body: this wave's 16 q vs tile's 64 keys, P via private slab
  auto body = [&](int buf, int t) __attribute__((always_inline)) {
    int j0 = t * KT;
    // QK^T over 4 key blocks: lane ends with S^T[key=kbk*16+quad*4+r][q=w*16+l16]
#pragma unroll
    for (int kbk = 0; kbk < 4; ++kbk) {
      bf16_8 kf0 = cat2(&ldsK[buf][(kbk * 16 + l16) * STR + quad * 8]);
      bf16_8 kf1 = cat2(&ldsK[buf][(kbk * 16 + l16) * STR + 32 + quad * 8]);
      f32x4 st = mfma16x16x32(kf1, qf[1], mfma16x16x32(kf0, qf[0], zero));
      f32x4 ck = *(const f32x4*)(kb + j0 + kbk * 16 + quad * 4);
      f32x4 p;
#pragma unroll
      for (int r = 0; r < 4; ++r) {
        // masked key: fma -> -1.44e31, exp2 -> 0. inactive q: actq=0 -> logit 0 (= ref).
        float v = actq * fmaf(st[r], SCALE2, ck[r]);
        p[r] = fast_exp2(v);
      }
      lsum += p[0] + p[1] + p[2] + p[3];
      // P[q-local = l16][key-local = kbk*16 + quad*4 .. +4] -> one b64 store
      *(s16x4*)(&Pw[l16 * STR + kbk * 16 + quad * 4]) = pack_bf16x4(p);
    }
    lds_flush();  // own P writes complete (cross-lane within wave; NO barrier)
    // PV: wave's P (A-frag) vs all 64 d of V (B-frags)
#pragma unroll
    for (int kc = 0; kc < 2; ++kc) {
      bf16_8 pf = cat2(&Pw[l16 * STR + kc * 32 + quad * 8]);
#pragma unroll
      for (int dt = 0; dt < 4; ++dt) {
        bf16_8 vf = cat2(&ldsV[buf][(dt * 16 + l16) * STR + kc * 32 + quad * 8]);
        acc[dt] = mfma16x16x32(pf, vf, acc[dt]);
      }
    }
  };

  for (int t = 0; t < NKT; t += 2) {
    // ---- even iter: compute buf 0 / tile t; prefetch t+2 -> set B ----
    {
      int j2 = (t + 2 < NKT) ? (t + 2) * KT : 0;  // wrap: valid addr, unused
      kB0 = *(const s16x8*)(Kb + (size_t)(j2 + srow) * HD + sc * 8);
      kB1 = *(const s16x8*)(Kb + (size_t)(j2 + srow + 32) * HD + sc * 8);
      vB0 = *(const s16x8*)(Vb + (size_t)srow * SEQ + j2 + sc * 8);
      vB1 = *(const s16x8*)(Vb + (size_t)(srow + 32) * SEQ + j2 + sc * 8);
    }
    body(0, t);
    // write tile t+1 (set A, loaded ~2 bodies ago) into buf 1
    write2(&ldsK[1][srow * STR + sc * 8], kA0);
    write2(&ldsK[1][(srow + 32) * STR + sc * 8], kA1);
    write2(&ldsV[1][srow * STR + sc * 8], vA0);
    write2(&ldsV[1][(srow + 32) * STR + sc * 8], vA1);
    lds_barrier();
    // ---- odd iter: compute buf 1 / tile t+1; prefetch t+3 -> set A ----
    {
      int j3 = (t + 3 < NKT) ? (t + 3) * KT : 0;
      kA0 = *(const s16x8*)(Kb + (size_t)(j3 + srow) * HD + sc * 8);
      kA1 = *(const s16x8*)(Kb + (size_t)(j3 + srow + 32) * HD + sc * 8);
      vA0 = *(const s16x8*)(Vb + (size_t)srow * SEQ + j3 + sc * 8);
      vA1 = *(const s16x8*)(Vb + (size_t)(srow + 32) * SEQ + j3 + sc * 8);
    }
    body(1, t + 1);
    // write tile t+2 (set B) into buf 0 (last pair: unused garbage, harmless)
    write2(&ldsK[0][srow * STR + sc * 8], kB0);
    write2(&ldsK[0][(srow + 32) * STR + sc * 8], kB1);
    write2(&ldsV[0][srow * STR + sc * 8], vB0);
    write2(&ldsV[0][(srow + 32) * STR + sc * 8], vB1);
    lds_barrier();
  }

  // --- normalize + store: lsum quad-reduce fully in-wave (no LDS, no barrier) ---
  float v = lsum;
  v += __shfl_xor(v, 16);
  v += __shfl_xor(v, 32);     // all lanes: total for q = w*16 + l16
  float linv = 1.0f / v;
  float lr[4];
#pragma unroll
  for (int r = 0; r < 4; ++r) lr[r] = __shfl(linv, quad * 4 + r);
#pragma unroll
  for (int dt = 0; dt < 4; ++dt)
#pragma unroll
    for (int r = 0; r < 4; ++r)
      out[((size_t)bz * SEQ + q0 + w * 16 + quad * 4 + r) * HID + h * HD + dt * 16 + l16] =
          acc[dt][r] * lr[r];
}

extern "C" void kernel_launch(void* const* d_in, const int* in_sizes, int n_in,
                              void* d_out, int out_size, void* d_ws, size_t ws_size,
                              hipStream_t stream) {
  (void)in_sizes; (void)n_in; (void)out_size;
  const float* toks = (const float*)d_in[0];
  const int* masks = (const int*)d_in[1];
  const float* Wq = (const float*)d_in[2];
  const float* bq = (const float*)d_in[3];
  const float* Wk = (const float*)d_in[4];
  const float* bk = (const float*)d_in[5];
  const float* Wv = (const float*)d_in[6];
  const float* bv = (const float*)d_in[7];
  char* ws = (char*)d_ws;
  const size_t KADD_B = (size_t)BATCH * SEQ * 4;
  const size_t WT_B = (size_t)HID * HID * 2;
  const size_t KV_FULL_B = (size_t)BATCH * NHEADS * SEQ * HD * 2;
  const size_t KV_HEAD_B = (size_t)BATCH * SEQ * HD * 2;
  const size_t TIER_A_NEED = KADD_B + 3 * WT_B + 2 * KV_FULL_B;  // ~28.7 MB
  float* kaddG = (float*)(ws);
  __bf16* WtQ = (__bf16*)(ws + KADD_B + 0 * WT_B);
  __bf16* WtK = (__bf16*)(ws + KADD_B + 1 * WT_B);
  __bf16* WtV = (__bf16*)(ws + KADD_B + 2 * WT_B);
  float* outp = (float*)d_out;

  mask_kadd<<<BATCH * SEQ / 256, 256, 0, stream>>>(masks, kaddG);
  dim3 tgrid(HID / 32, HID / 32, 3), tblk(32, 8);
  transpose768x3<<<tgrid, tblk, 0, stream>>>(Wq, Wk, Wv, WtQ);

  if (ws_size >= TIER_A_NEED) {
    __bf16* Kf = (__bf16*)(ws + KADD_B + 3 * WT_B);
    __bf16* Vtf = (__bf16*)(ws + KADD_B + 3 * WT_B + KV_FULL_B);
    dim3 pgrid(BATCH * SEQ / 64, NHEADS);
    proj_kv<<<pgrid, 256, 0, stream>>>(toks, WtK, bk, WtV, bv, Kf, Vtf, 0, NHEADS);
    dim3 agrid(SEQ / 64, NHEADS, BATCH);
    attn_fused<<<agrid, 256, 0, stream>>>(toks, WtQ, bq, Kf, Vtf, kaddG, outp, 0, NHEADS);
  } else {
    __bf16* Kh = (__bf16*)(ws + KADD_B + 3 * WT_B);
    __bf16* Vth = (__bf16*)(ws + KADD_B + 3 * WT_B + KV_HEAD_B);
    dim3 pgrid(BATCH * SEQ / 64, 1);
    dim3 agrid(SEQ / 64, 1, BATCH);
    for (int h = 0; h < NHEADS; ++h) {
      proj_kv<<<pgrid, 256, 0, stream>>>(toks, WtK, bk, WtV, bv, Kh, Vth, h, 1);
      attn_fused<<<agrid, 256, 0, stream>>>(toks, WtQ, bq, Kh, Vth, kaddG, outp, h, 1);
    }
  }
}